// Round 7
// baseline (350.850 us; speedup 1.0000x reference)
//
#include <hip/hip_runtime.h>

typedef int v4i  __attribute__((ext_vector_type(4)));
typedef int v16i __attribute__((ext_vector_type(16)));

__device__ __forceinline__ int pack4i(int a, int b, int c, int d) {
  return (a & 255) | ((b & 255) << 8) | ((c & 255) << 16) | ((d & 255) << 24);
}
// SWAR per-byte add (mod-256 per lane-byte)
__device__ __forceinline__ int badd4(int a, int b) {
  return ((a & 0x7f7f7f7f) + (b & 0x7f7f7f7f)) ^ ((a ^ b) & 0x80808080);
}

// ---------------------------------------------------------------------------
// Pack (W + E) -> int8, transposed Bt[n][k] (row stride K bytes).
// Tile: 64 n x 256 k per block, 256 threads. Zero-pads n >= N rows.
// ---------------------------------------------------------------------------
__device__ void pack_tile(const int* __restrict__ W, const int* __restrict__ E,
                          char* __restrict__ Bt, int K, int N,
                          int nx, int ky, char* lin) {
  const int t = threadIdx.x;
  const int n0 = nx * 64, k0 = ky * 256;
  {
    const int kk = t >> 2, c = t & 3;
    for (int p = 0; p < 4; ++p) {
      const int k = kk + (p << 6);
      const long grow = (long)(k0 + k) * N;
      #pragma unroll
      for (int i = 0; i < 4; ++i) {
        const int nl = (c << 4) + (i << 2);
        const int ng = n0 + nl;
        int a0, a1, a2, a3;
        if (ng + 3 < N) {
          int4 wv = *(const int4*)(W + grow + ng);
          int4 ev = *(const int4*)(E + grow + ng);
          a0 = wv.x + ev.x; a1 = wv.y + ev.y; a2 = wv.z + ev.z; a3 = wv.w + ev.w;
        } else {
          a0 = (ng + 0 < N) ? W[grow + ng + 0] + E[grow + ng + 0] : 0;
          a1 = (ng + 1 < N) ? W[grow + ng + 1] + E[grow + ng + 1] : 0;
          a2 = (ng + 2 < N) ? W[grow + ng + 2] + E[grow + ng + 2] : 0;
          a3 = (ng + 3 < N) ? W[grow + ng + 3] + E[grow + ng + 3] : 0;
        }
        *(int*)(lin + k * 68 + nl) = pack4i(a0, a1, a2, a3);
      }
    }
  }
  __syncthreads();
  {
    const int n = t & 63, kq = t >> 6;
    char* dst = Bt + (long)(n0 + n) * K + k0 + (kq << 6);
    int outv[16];
    #pragma unroll
    for (int g = 0; g < 16; ++g) {
      const int k = (kq << 6) + (g << 2);
      outv[g] = pack4i(lin[(k + 0) * 68 + n], lin[(k + 1) * 68 + n],
                       lin[(k + 2) * 68 + n], lin[(k + 3) * 68 + n]);
    }
    #pragma unroll
    for (int g = 0; g < 4; ++g)
      *(int4*)(dst + (g << 4)) =
          make_int4(outv[g * 4], outv[g * 4 + 1], outv[g * 4 + 2], outv[g * 4 + 3]);
  }
}

// ---------------------------------------------------------------------------
// pack_all: weight tiles + biases only (X/H conversion now fused into GEMMs).
// ---------------------------------------------------------------------------
__global__ __launch_bounds__(256) void pack_all_kernel(
    const int* W1, const int* E1, char* Bt1,
    const int* W2, const int* E2, char* Bt2,
    const int* W3, const int* E3, char* Bt3,
    const int* b1, const int* eb1, int* bs1,
    const int* b2, const int* eb2, int* bs2,
    const int* b3, const int* eb3, int* bs3) {
  __shared__ __align__(16) char lin[256 * 68];
  const int bid = blockIdx.x;
  if (bid < 192) {
    pack_tile(W1, E1, Bt1, 3072, 1024, bid % 16, bid / 16, lin);
  } else if (bid < 256) {
    const int l = bid - 192;
    pack_tile(W2, E2, Bt2, 1024, 1024, l % 16, l / 16, lin);
  } else if (bid < 264) {
    const int l = bid - 256;
    pack_tile(W3, E3, Bt3, 1024, 100, l & 1, l >> 1, lin);
  } else {
    const int t = threadIdx.x;
    for (int i = t; i < 1024; i += 256) {
      bs1[i] = b1[i] + eb1[i];
      bs2[i] = b2[i] + eb2[i];
    }
    for (int i = t; i < 128; i += 256)
      bs3[i] = (i < 100) ? (b3[i] + eb3[i]) : 0;
  }
}

// ---------------------------------------------------------------------------
// GEMM: 64x128 tile, BK=64, 256 thr (4 waves, each 64x32), 2-stage LDS dbuf
// (verified R5 shape). Grid 1024; mt = bid&127 so the 8 blocks sharing an
// A-tile are congruent mod 8 -> same XCD L2.
// MODE 1 (layer 1): A = X int32, packed to int8 in staging; epilogue adds
//   H (int32) via SWAR and writes A2 int8 through an LDS transpose.
// MODE 2 (layer 2): A = A2 int8; epilogue writes int32 h2 direct.
// ---------------------------------------------------------------------------
template<int MODE>
__global__ __launch_bounds__(256, 4) void gemm_kernel(
    const void* __restrict__ Asrc, const char* __restrict__ Btg,
    const int* __restrict__ bsum, const int* __restrict__ H,
    char* __restrict__ A8out, int* __restrict__ Iout, const int K) {
  // stage: As [64][80] (5120) + Bs [128][80] (10240) = 15360; x2 = 30720
  __shared__ __align__(16) char smem[30720];

  const int t = threadIdx.x;
  const int bid = blockIdx.x;
  const int mt = bid & 127, nt = bid >> 7;
  const long m0 = (long)mt << 6;
  const int n0 = nt << 7;

  const int lane = t & 63, w = t >> 6;
  const int lc = lane & 31, hg = lane >> 5;

  v16i acc[2] = {};

  // A staging: 64 rows x 4 thr (MODE1: 64 ints -> 16 B; MODE2: 16 B)
  const int am = t >> 2, ah = t & 3;
  const int aoff = am * 80 + ah * 16;
  const int*  Arow32 = (const int*)Asrc + (m0 + am) * (long)K + ah * 16;
  const char* Arow8  = (const char*)Asrc + (m0 + am) * (long)K + ah * 16;
  // B staging: 128 rows x 2 thr x 32 B
  const int bm = t >> 1, bh = t & 1;
  const char* Brow = Btg + (long)(n0 + bm) * K + bh * 32;
  const int boff = bm * 80 + bh * 32;

  const int abo = lc * 80 + hg * 16;
  const int bbo = (w * 32 + lc) * 80 + hg * 16;

  int4 ar[4], br0, br1;
  auto LOAD = [&](int kt) {
    const int kb = kt << 6;
    if (MODE == 1) {
      const int* p = Arow32 + kb;
      ar[0] = ((const int4*)p)[0];
      ar[1] = ((const int4*)p)[1];
      ar[2] = ((const int4*)p)[2];
      ar[3] = ((const int4*)p)[3];
    } else {
      ar[0] = *(const int4*)(Arow8 + kb);
    }
    br0 = *(const int4*)(Brow + kb);
    br1 = *(const int4*)(Brow + kb + 16);
  };
  auto STORE = [&](int stage) {
    char* base = smem + stage * 15360;
    if (MODE == 1) {
      *(int4*)(base + aoff) = make_int4(
          pack4i(ar[0].x, ar[0].y, ar[0].z, ar[0].w),
          pack4i(ar[1].x, ar[1].y, ar[1].z, ar[1].w),
          pack4i(ar[2].x, ar[2].y, ar[2].z, ar[2].w),
          pack4i(ar[3].x, ar[3].y, ar[3].z, ar[3].w));
    } else {
      *(int4*)(base + aoff) = ar[0];
    }
    *(int4*)(base + 5120 + boff)      = br0;
    *(int4*)(base + 5120 + boff + 16) = br1;
  };
  auto MFMA = [&](int stage) {
    const char* base = smem + stage * 15360;
    const char* Ab = base + abo;
    const char* Bb = base + 5120 + bbo;
    #pragma unroll
    for (int ks = 0; ks < 2; ++ks) {
      v4i a0 = *(const v4i*)(Ab + ks * 32);
      v4i a1 = *(const v4i*)(Ab + 32 * 80 + ks * 32);
      v4i b  = *(const v4i*)(Bb + ks * 32);
      acc[0] = __builtin_amdgcn_mfma_i32_32x32x32_i8(a0, b, acc[0], 0, 0, 0);
      acc[1] = __builtin_amdgcn_mfma_i32_32x32x32_i8(a1, b, acc[1], 0, 0, 0);
    }
  };

  const int kiters = K >> 6;
  LOAD(0);
  STORE(0);
  __syncthreads();

  for (int kt = 0; kt < kiters; ++kt) {
    if (kt + 1 < kiters) LOAD(kt + 1);   // in flight during MFMA
    MFMA(kt & 1);
    if (kt + 1 < kiters) {
      STORE((kt + 1) & 1);   // buffer fenced by previous barrier
      __syncthreads();
    }
  }

  // Epilogue. C/D layout: col = lane&31, row = (reg&3) + 8*(reg>>2) + 4*hg.
  const int gcl = w * 32 + lc;
  const int bs = bsum[n0 + gcl];
  if (MODE == 2) {
    #pragma unroll
    for (int tm = 0; tm < 2; ++tm) {
      #pragma unroll
      for (int r = 0; r < 16; ++r) {
        const int row = tm * 32 + (hg << 2) + (r & 3) + ((r >> 2) << 3);
        Iout[(m0 + row) * 1024 + n0 + gcl] = (int)(signed char)(acc[tm][r] + bs);
      }
    }
  } else {
    __syncthreads();   // smem reused as 64x144 transpose buffer
    #pragma unroll
    for (int tm = 0; tm < 2; ++tm) {
      #pragma unroll
      for (int r = 0; r < 16; ++r) {
        const int row = tm * 32 + (hg << 2) + (r & 3) + ((r >> 2) << 3);
        smem[row * 144 + gcl] = (char)(acc[tm][r] + bs);
      }
    }
    __syncthreads();
    // readout: thread -> row t>>2, 32 bytes at (t&3)*32 ; add H (int32) SWAR
    const int rr = t >> 2, rc = (t & 3) * 32;
    const char* src = smem + rr * 144 + rc;
    const long gco = (m0 + rr) * 1024 + n0 + rc;
    int4 s0 = *(const int4*)(src);
    int4 s1 = *(const int4*)(src + 16);
    const int* Hp = H + gco;
    int4 h0 = ((const int4*)Hp)[0], h1 = ((const int4*)Hp)[1];
    int4 h2v = ((const int4*)Hp)[2], h3 = ((const int4*)Hp)[3];
    int4 h4 = ((const int4*)Hp)[4], h5 = ((const int4*)Hp)[5];
    int4 h6 = ((const int4*)Hp)[6], h7 = ((const int4*)Hp)[7];
    s0.x = badd4(s0.x, pack4i(h0.x, h0.y, h0.z, h0.w));
    s0.y = badd4(s0.y, pack4i(h1.x, h1.y, h1.z, h1.w));
    s0.z = badd4(s0.z, pack4i(h2v.x, h2v.y, h2v.z, h2v.w));
    s0.w = badd4(s0.w, pack4i(h3.x, h3.y, h3.z, h3.w));
    s1.x = badd4(s1.x, pack4i(h4.x, h4.y, h4.z, h4.w));
    s1.y = badd4(s1.y, pack4i(h5.x, h5.y, h5.z, h5.w));
    s1.z = badd4(s1.z, pack4i(h6.x, h6.y, h6.z, h6.w));
    s1.w = badd4(s1.w, pack4i(h7.x, h7.y, h7.z, h7.w));
    *(int4*)(A8out + gco)      = s0;
    *(int4*)(A8out + gco + 16) = s1;
  }
}

// ---------------------------------------------------------------------------
// Layer 3: 16x128 tile, 512 blocks (2/CU), mfma_i32_16x16x64_i8, 2-stage.
// A = h2 int32 from d_out, packed to int8 in staging.
// A-frag: row = lane&15, k = (lane>>4)*16 + j. C/D: col = lane&15,
// row = (lane>>4)*4 + reg (same pattern as verified 32x32x32).
// ---------------------------------------------------------------------------
__global__ __launch_bounds__(256, 2) void gemm3_kernel(
    const int* __restrict__ h2, const char* __restrict__ Btg,
    const int* __restrict__ bsum, int* __restrict__ Iout) {
  // stage: As 16x80 (1280) + Bs 128x80 (10240) = 11520; x2 = 23040
  __shared__ __align__(16) char smem[23040];
  const int t = threadIdx.x;
  const int m0 = blockIdx.x << 4;
  const int lane = t & 63, w = t >> 6;
  const int l16 = lane & 15, q = lane >> 4;
  v4i acc0 = {}, acc1 = {};

  const int am = t >> 4, ah = t & 15;      // 16 rows x 16 thr x 4 ints
  const int* Arow = h2 + (long)(m0 + am) * 1024 + ah * 4;
  const int aoff = am * 80 + ah * 4;
  const int bm = t >> 1, bh = t & 1;       // 128 rows x 2 thr x 32 B
  const char* Brow = Btg + (long)bm * 1024 + bh * 32;
  const int boff = bm * 80 + bh * 32;

  const int abo  = l16 * 80 + q * 16;
  const int bbo0 = (w * 32 + l16) * 80 + q * 16;
  const int bbo1 = (w * 32 + 16 + l16) * 80 + q * 16;

  int4 ar, br0, br1;
  auto LOAD = [&](int kt) {
    const int kb = kt << 6;
    ar  = *(const int4*)(Arow + kb);
    br0 = *(const int4*)(Brow + kb);
    br1 = *(const int4*)(Brow + kb + 16);
  };
  auto STORE = [&](int stage) {
    char* base = smem + stage * 11520;
    *(int*)(base + aoff) = pack4i(ar.x, ar.y, ar.z, ar.w);
    *(int4*)(base + 1280 + boff)      = br0;
    *(int4*)(base + 1280 + boff + 16) = br1;
  };
  auto MFMA = [&](int stage) {
    const char* base = smem + stage * 11520;
    v4i a  = *(const v4i*)(base + abo);
    v4i b0 = *(const v4i*)(base + 1280 + bbo0);
    v4i b1 = *(const v4i*)(base + 1280 + bbo1);
    acc0 = __builtin_amdgcn_mfma_i32_16x16x64_i8(a, b0, acc0, 0, 0, 0);
    acc1 = __builtin_amdgcn_mfma_i32_16x16x64_i8(a, b1, acc1, 0, 0, 0);
  };

  LOAD(0); STORE(0); __syncthreads();
  for (int kt = 0; kt < 16; ++kt) {
    if (kt + 1 < 16) LOAD(kt + 1);
    MFMA(kt & 1);
    if (kt + 1 < 16) { STORE((kt + 1) & 1); __syncthreads(); }
  }

  const int c0 = w * 32 + l16;       // cols {0-15,32-47,64-79,96-111}
  const int c1 = c0 + 16;            // cols {16-31,48-63,80-95,112-127}
  if (c0 < 100) {
    const int b = bsum[c0];
    #pragma unroll
    for (int r = 0; r < 4; ++r)
      Iout[(long)(m0 + q * 4 + r) * 100 + c0] = (int)(signed char)(acc0[r] + b);
  }
  if (c1 < 100) {
    const int b = bsum[c1];
    #pragma unroll
    for (int r = 0; r < 4; ++r)
      Iout[(long)(m0 + q * 4 + r) * 100 + c1] = (int)(signed char)(acc1[r] + b);
  }
}

// ---------------------------------------------------------------------------
// ws (12.7 MB): Bt1 | Bt2 | Bt3 | bs1 | bs2 | bs3 | A2
// ---------------------------------------------------------------------------
extern "C" void kernel_launch(void* const* d_in, const int* in_sizes, int n_in,
                              void* d_out, int out_size, void* d_ws, size_t ws_size,
                              hipStream_t stream) {
  (void)in_sizes; (void)n_in; (void)out_size; (void)ws_size;
  const int* W1  = (const int*)d_in[0];
  const int* b1  = (const int*)d_in[1];
  const int* W2  = (const int*)d_in[2];
  const int* b2  = (const int*)d_in[3];
  const int* W3  = (const int*)d_in[4];
  const int* b3  = (const int*)d_in[5];
  const int* E1  = (const int*)d_in[6];
  const int* eb1 = (const int*)d_in[7];
  const int* E2  = (const int*)d_in[8];
  const int* eb2 = (const int*)d_in[9];
  const int* E3  = (const int*)d_in[10];
  const int* eb3 = (const int*)d_in[11];
  const int* X   = (const int*)d_in[12];   // [8192][3072] int32
  const int* H   = (const int*)d_in[13];   // [8192][1024] int32
  int* out = (int*)d_out;                  // h2 [8192*1024] then out [8192*100]

  char* ws  = (char*)d_ws;
  char* Bt1 = ws;                          // 3,145,728
  char* Bt2 = Bt1 + 3145728;               // 1,048,576
  char* Bt3 = Bt2 + 1048576;               //   131,072 (rows 100..127 zeroed)
  int*  bs1 = (int*)(Bt3 + 131072);        // 1024 ints
  int*  bs2 = bs1 + 1024;                  // 1024 ints
  int*  bs3 = bs2 + 1024;                  //  128 ints
  char* A2  = (char*)(bs3 + 128);          // 8,388,608 int8

  pack_all_kernel<<<dim3(265), dim3(256), 0, stream>>>(
      W1, E1, Bt1, W2, E2, Bt2, W3, E3, Bt3,
      b1, eb1, bs1, b2, eb2, bs2, b3, eb3, bs3);

  // Layer 1: X (int32, narrowed in staging) + hiddens-add -> A2 (int8)
  gemm_kernel<1><<<dim3(1024), dim3(256), 0, stream>>>(
      X, Bt1, bs1, H, A2, nullptr, 3072);

  // Layer 2: h2 -> d_out (int32)
  gemm_kernel<2><<<dim3(1024), dim3(256), 0, stream>>>(
      A2, Bt2, bs2, nullptr, nullptr, out, 1024);

  // Layer 3: reads h2 from d_out (int32), writes out region (int32)
  gemm3_kernel<<<dim3(512), dim3(256), 0, stream>>>(
      out, Bt3, bs3, out + 8388608);
}

// Round 8
// 309.445 us; speedup vs baseline: 1.1338x; 1.1338x over previous
//
#include <hip/hip_runtime.h>

typedef int v4i  __attribute__((ext_vector_type(4)));
typedef int v16i __attribute__((ext_vector_type(16)));

__device__ __forceinline__ int pack4i(int a, int b, int c, int d) {
  return (a & 255) | ((b & 255) << 8) | ((c & 255) << 16) | ((d & 255) << 24);
}
// SWAR per-byte add (mod-256 per lane-byte)
__device__ __forceinline__ int badd4(int a, int b) {
  return ((a & 0x7f7f7f7f) + (b & 0x7f7f7f7f)) ^ ((a ^ b) & 0x80808080);
}

__device__ __forceinline__ void async_ld16(const void* g, void* l) {
  __builtin_amdgcn_global_load_lds(
      (const __attribute__((address_space(1))) void*)g,
      (__attribute__((address_space(3))) void*)l, 16, 0, 0);
}

// ---------------------------------------------------------------------------
// Pack (W + E) -> int8, transposed Bt[n][k] (row stride K bytes).
// Tile: 64 n x 256 k per block, 256 threads. Zero-pads n >= N rows.
// ---------------------------------------------------------------------------
__device__ void pack_tile(const int* __restrict__ W, const int* __restrict__ E,
                          char* __restrict__ Bt, int K, int N,
                          int nx, int ky, char* lin) {
  const int t = threadIdx.x;
  const int n0 = nx * 64, k0 = ky * 256;
  {
    const int kk = t >> 2, c = t & 3;
    for (int p = 0; p < 4; ++p) {
      const int k = kk + (p << 6);
      const long grow = (long)(k0 + k) * N;
      #pragma unroll
      for (int i = 0; i < 4; ++i) {
        const int nl = (c << 4) + (i << 2);
        const int ng = n0 + nl;
        int a0, a1, a2, a3;
        if (ng + 3 < N) {
          int4 wv = *(const int4*)(W + grow + ng);
          int4 ev = *(const int4*)(E + grow + ng);
          a0 = wv.x + ev.x; a1 = wv.y + ev.y; a2 = wv.z + ev.z; a3 = wv.w + ev.w;
        } else {
          a0 = (ng + 0 < N) ? W[grow + ng + 0] + E[grow + ng + 0] : 0;
          a1 = (ng + 1 < N) ? W[grow + ng + 1] + E[grow + ng + 1] : 0;
          a2 = (ng + 2 < N) ? W[grow + ng + 2] + E[grow + ng + 2] : 0;
          a3 = (ng + 3 < N) ? W[grow + ng + 3] + E[grow + ng + 3] : 0;
        }
        *(int*)(lin + k * 68 + nl) = pack4i(a0, a1, a2, a3);
      }
    }
  }
  __syncthreads();
  {
    const int n = t & 63, kq = t >> 6;
    char* dst = Bt + (long)(n0 + n) * K + k0 + (kq << 6);
    int outv[16];
    #pragma unroll
    for (int g = 0; g < 16; ++g) {
      const int k = (kq << 6) + (g << 2);
      outv[g] = pack4i(lin[(k + 0) * 68 + n], lin[(k + 1) * 68 + n],
                       lin[(k + 2) * 68 + n], lin[(k + 3) * 68 + n]);
    }
    #pragma unroll
    for (int g = 0; g < 4; ++g)
      *(int4*)(dst + (g << 4)) =
          make_int4(outv[g * 4], outv[g * 4 + 1], outv[g * 4 + 2], outv[g * 4 + 3]);
  }
}

// ---------------------------------------------------------------------------
// Async int32 -> int8 narrowing copy. Per iter: stage 32 KB (8192 ints) into
// LDS via global_load_lds (no VGPR round trip, 32 KB in flight per block),
// barrier (drains vmcnt), pack LDS -> 8 KB global store.
// ---------------------------------------------------------------------------
__device__ void pack_async(const int* __restrict__ src, char* __restrict__ dst,
                           long base_ints, int iters, char* stage) {
  const int t = threadIdx.x;
  const int w = t >> 6, lane = t & 63;
  for (int it = 0; it < iters; ++it) {
    const long c0 = base_ints + (long)it * 8192;
    #pragma unroll
    for (int r = 0; r < 8; ++r) {
      const int off = (r * 4 + w) * 1024;               // wave-uniform byte off
      const int* g = src + c0 + ((off + lane * 16) >> 2);
      async_ld16(g, stage + off);                       // lds = base + lane*16
    }
    __syncthreads();
    const char* s = stage + t * 128;
    int o[8];
    #pragma unroll
    for (int g8 = 0; g8 < 8; ++g8) {
      int4 v = *(const int4*)(s + g8 * 16);
      o[g8] = pack4i(v.x, v.y, v.z, v.w);
    }
    *(int4*)(dst + c0 + t * 32)      = make_int4(o[0], o[1], o[2], o[3]);
    *(int4*)(dst + c0 + t * 32 + 16) = make_int4(o[4], o[5], o[6], o[7]);
    __syncthreads();
  }
}

// ---------------------------------------------------------------------------
// pack_all: weight tiles + biases + async X->X8 / H->H8.
// ---------------------------------------------------------------------------
__global__ __launch_bounds__(256) void pack_all_kernel(
    const int* W1, const int* E1, char* Bt1,
    const int* W2, const int* E2, char* Bt2,
    const int* W3, const int* E3, char* Bt3,
    const int* b1, const int* eb1, int* bs1,
    const int* b2, const int* eb2, int* bs2,
    const int* b3, const int* eb3, int* bs3,
    const int* X, char* X8, const int* H, char* H8) {
  __shared__ __align__(16) char smem[32768];
  const int bid = blockIdx.x;
  if (bid < 192) {
    pack_tile(W1, E1, Bt1, 3072, 1024, bid % 16, bid / 16, smem);
  } else if (bid < 256) {
    const int l = bid - 192;
    pack_tile(W2, E2, Bt2, 1024, 1024, l % 16, l / 16, smem);
  } else if (bid < 264) {
    const int l = bid - 256;
    pack_tile(W3, E3, Bt3, 1024, 100, l & 1, l >> 1, smem);
  } else if (bid == 264) {
    const int t = threadIdx.x;
    for (int i = t; i < 1024; i += 256) {
      bs1[i] = b1[i] + eb1[i];
      bs2[i] = b2[i] + eb2[i];
    }
    for (int i = t; i < 128; i += 256)
      bs3[i] = (i < 100) ? (b3[i] + eb3[i]) : 0;
  } else if (bid < 1033) {
    // X: 25,165,824 ints = 3072 chunks of 8192; 768 blocks x 4 iters
    pack_async(X, X8, (long)(bid - 265) * 32768, 4, smem);
  } else {
    // H: 8,388,608 ints = 1024 chunks; 256 blocks x 4 iters
    pack_async(H, H8, (long)(bid - 1033) * 32768, 4, smem);
  }
}

// ---------------------------------------------------------------------------
// GEMM: 64x128 tile, BK=64, 256 thr (4 waves, each 64x32), 2-stage LDS dbuf
// (verified R5 shape). Grid 1024; mt = bid&127 so the 8 blocks sharing an
// A-tile are congruent mod 8 -> same XCD L2.
// EPI 0: A8out = trunc8(acc+bs) SWAR+ H8, int8, via LDS transpose  (layer 1)
// EPI 1: Iout  = trunc8(acc+bs) as int32, direct                   (layer 2)
// ---------------------------------------------------------------------------
template<int EPI>
__global__ __launch_bounds__(256, 4) void gemm_kernel(
    const char* __restrict__ A, const char* __restrict__ Btg,
    const int* __restrict__ bsum, const char* __restrict__ H8,
    char* __restrict__ A8out, int* __restrict__ Iout, const int K) {
  // stage: As [64][80] (5120) + Bs [128][80] (10240) = 15360; x2 = 30720
  __shared__ __align__(16) char smem[30720];

  const int t = threadIdx.x;
  const int bid = blockIdx.x;
  const int mt = bid & 127, nt = bid >> 7;
  const long m0 = (long)mt << 6;
  const int n0 = nt << 7;

  const int lane = t & 63, w = t >> 6;
  const int lc = lane & 31, hg = lane >> 5;

  v16i acc[2] = {};

  // A staging: 64 rows x 4 thr x 16B ; B staging: 128 rows x 2 thr x 32B
  const int am = t >> 2, ah = t & 3;
  const char* Arow = A + (m0 + am) * (long)K + ah * 16;
  const int aoff = am * 80 + ah * 16;
  const int bm = t >> 1, bh = t & 1;
  const char* Brow = Btg + (long)(n0 + bm) * K + bh * 32;
  const int boff = bm * 80 + bh * 32;

  const int abo = lc * 80 + hg * 16;
  const int bbo = (w * 32 + lc) * 80 + hg * 16;

  int4 ar, br0, br1;
  auto LOAD = [&](int kb) {
    ar  = *(const int4*)(Arow + kb);
    br0 = *(const int4*)(Brow + kb);
    br1 = *(const int4*)(Brow + kb + 16);
  };
  auto STORE = [&](int stage) {
    char* base = smem + stage * 15360;
    *(int4*)(base + aoff) = ar;
    *(int4*)(base + 5120 + boff)      = br0;
    *(int4*)(base + 5120 + boff + 16) = br1;
  };

  const int kiters = K >> 6;
  LOAD(0);
  STORE(0);
  __syncthreads();

  for (int kt = 0; kt < kiters; ++kt) {
    if (kt + 1 < kiters) LOAD((kt + 1) << 6);   // in flight during MFMA
    const char* base = smem + (kt & 1) * 15360;
    const char* Ab = base + abo;
    const char* Bb = base + 5120 + bbo;
    #pragma unroll
    for (int ks = 0; ks < 2; ++ks) {
      v4i a0 = *(const v4i*)(Ab + ks * 32);
      v4i a1 = *(const v4i*)(Ab + 32 * 80 + ks * 32);
      v4i b  = *(const v4i*)(Bb + ks * 32);
      acc[0] = __builtin_amdgcn_mfma_i32_32x32x32_i8(a0, b, acc[0], 0, 0, 0);
      acc[1] = __builtin_amdgcn_mfma_i32_32x32x32_i8(a1, b, acc[1], 0, 0, 0);
    }
    if (kt + 1 < kiters) {
      STORE((kt + 1) & 1);   // buffer fenced by previous barrier
      __syncthreads();
    }
  }

  // Epilogue. C/D layout: col = lane&31, row = (reg&3) + 8*(reg>>2) + 4*hg.
  const int gcl = w * 32 + lc;
  const int bs = bsum[n0 + gcl];
  if (EPI == 1) {
    #pragma unroll
    for (int tm = 0; tm < 2; ++tm) {
      #pragma unroll
      for (int r = 0; r < 16; ++r) {
        const int row = tm * 32 + (hg << 2) + (r & 3) + ((r >> 2) << 3);
        Iout[(m0 + row) * 1024 + n0 + gcl] = (int)(signed char)(acc[tm][r] + bs);
      }
    }
  } else {
    __syncthreads();   // smem reused as 64x144 transpose buffer
    #pragma unroll
    for (int tm = 0; tm < 2; ++tm) {
      #pragma unroll
      for (int r = 0; r < 16; ++r) {
        const int row = tm * 32 + (hg << 2) + (r & 3) + ((r >> 2) << 3);
        smem[row * 144 + gcl] = (char)(acc[tm][r] + bs);
      }
    }
    __syncthreads();
    // readout: thread -> row t>>2, 32 bytes at (t&3)*32 ; SWAR-add H8
    const char* src = smem + (t >> 2) * 144 + (t & 3) * 32;
    const long gm = m0 + (t >> 2);
    const long gco = gm * 1024 + n0 + (t & 3) * 32;
    int4 s0 = *(const int4*)(src);
    int4 s1 = *(const int4*)(src + 16);
    int4 h0 = *(const int4*)(H8 + gco);
    int4 h1 = *(const int4*)(H8 + gco + 16);
    s0 = make_int4(badd4(s0.x, h0.x), badd4(s0.y, h0.y),
                   badd4(s0.z, h0.z), badd4(s0.w, h0.w));
    s1 = make_int4(badd4(s1.x, h1.x), badd4(s1.y, h1.y),
                   badd4(s1.z, h1.z), badd4(s1.w, h1.w));
    *(int4*)(A8out + gco)      = s0;
    *(int4*)(A8out + gco + 16) = s1;
  }
}

// ---------------------------------------------------------------------------
// Layer 3: 16x128 tile, 512 blocks (2/CU), mfma_i32_16x16x64_i8, 2-stage.
// A = h2 int32 from d_out, packed to int8 in staging. (Verified R7.)
// ---------------------------------------------------------------------------
__global__ __launch_bounds__(256, 2) void gemm3_kernel(
    const int* __restrict__ h2, const char* __restrict__ Btg,
    const int* __restrict__ bsum, int* __restrict__ Iout) {
  // stage: As 16x80 (1280) + Bs 128x80 (10240) = 11520; x2 = 23040
  __shared__ __align__(16) char smem[23040];
  const int t = threadIdx.x;
  const int m0 = blockIdx.x << 4;
  const int lane = t & 63, w = t >> 6;
  const int l16 = lane & 15, q = lane >> 4;
  v4i acc0 = {}, acc1 = {};

  const int am = t >> 4, ah = t & 15;      // 16 rows x 16 thr x 4 ints
  const int* Arow = h2 + (long)(m0 + am) * 1024 + ah * 4;
  const int aoff = am * 80 + ah * 4;
  const int bm = t >> 1, bh = t & 1;       // 128 rows x 2 thr x 32 B
  const char* Brow = Btg + (long)bm * 1024 + bh * 32;
  const int boff = bm * 80 + bh * 32;

  const int abo  = l16 * 80 + q * 16;
  const int bbo0 = (w * 32 + l16) * 80 + q * 16;
  const int bbo1 = (w * 32 + 16 + l16) * 80 + q * 16;

  int4 ar, br0, br1;
  auto LOAD = [&](int kt) {
    const int kb = kt << 6;
    ar  = *(const int4*)(Arow + kb);
    br0 = *(const int4*)(Brow + kb);
    br1 = *(const int4*)(Brow + kb + 16);
  };
  auto STORE = [&](int stage) {
    char* base = smem + stage * 11520;
    *(int*)(base + aoff) = pack4i(ar.x, ar.y, ar.z, ar.w);
    *(int4*)(base + 1280 + boff)      = br0;
    *(int4*)(base + 1280 + boff + 16) = br1;
  };
  auto MFMA = [&](int stage) {
    const char* base = smem + stage * 11520;
    v4i a  = *(const v4i*)(base + abo);
    v4i b0 = *(const v4i*)(base + 1280 + bbo0);
    v4i b1 = *(const v4i*)(base + 1280 + bbo1);
    acc0 = __builtin_amdgcn_mfma_i32_16x16x64_i8(a, b0, acc0, 0, 0, 0);
    acc1 = __builtin_amdgcn_mfma_i32_16x16x64_i8(a, b1, acc1, 0, 0, 0);
  };

  LOAD(0); STORE(0); __syncthreads();
  for (int kt = 0; kt < 16; ++kt) {
    if (kt + 1 < 16) LOAD(kt + 1);
    MFMA(kt & 1);
    if (kt + 1 < 16) { STORE((kt + 1) & 1); __syncthreads(); }
  }

  const int c0 = w * 32 + l16;       // cols {0-15,32-47,64-79,96-111}
  const int c1 = c0 + 16;            // cols {16-31,48-63,80-95,112-127}
  if (c0 < 100) {
    const int b = bsum[c0];
    #pragma unroll
    for (int r = 0; r < 4; ++r)
      Iout[(long)(m0 + q * 4 + r) * 100 + c0] = (int)(signed char)(acc0[r] + b);
  }
  if (c1 < 100) {
    const int b = bsum[c1];
    #pragma unroll
    for (int r = 0; r < 4; ++r)
      Iout[(long)(m0 + q * 4 + r) * 100 + c1] = (int)(signed char)(acc1[r] + b);
  }
}

// ---------------------------------------------------------------------------
// ws (12.7 MB): Bt1 | Bt2 | Bt3 | bs1 | bs2 | bs3 | A2
// d_out scratch: X8 [0,25.2M) + H8 [25.2M,33.6M) — both dead before L2
// overwrites the region with h2 (launch order on one stream guarantees it).
// ---------------------------------------------------------------------------
extern "C" void kernel_launch(void* const* d_in, const int* in_sizes, int n_in,
                              void* d_out, int out_size, void* d_ws, size_t ws_size,
                              hipStream_t stream) {
  (void)in_sizes; (void)n_in; (void)out_size; (void)ws_size;
  const int* W1  = (const int*)d_in[0];
  const int* b1  = (const int*)d_in[1];
  const int* W2  = (const int*)d_in[2];
  const int* b2  = (const int*)d_in[3];
  const int* W3  = (const int*)d_in[4];
  const int* b3  = (const int*)d_in[5];
  const int* E1  = (const int*)d_in[6];
  const int* eb1 = (const int*)d_in[7];
  const int* E2  = (const int*)d_in[8];
  const int* eb2 = (const int*)d_in[9];
  const int* E3  = (const int*)d_in[10];
  const int* eb3 = (const int*)d_in[11];
  const int* X   = (const int*)d_in[12];   // [8192][3072] int32
  const int* H   = (const int*)d_in[13];   // [8192][1024] int32
  int* out = (int*)d_out;                  // h2 [8192*1024] then out [8192*100]

  char* ws  = (char*)d_ws;
  char* Bt1 = ws;                          // 3,145,728
  char* Bt2 = Bt1 + 3145728;               // 1,048,576
  char* Bt3 = Bt2 + 1048576;               //   131,072 (rows 100..127 zeroed)
  int*  bs1 = (int*)(Bt3 + 131072);        // 1024 ints
  int*  bs2 = bs1 + 1024;                  // 1024 ints
  int*  bs3 = bs2 + 1024;                  //  128 ints
  char* A2  = (char*)(bs3 + 128);          // 8,388,608 int8
  char* X8  = (char*)d_out;                // 25,165,824 int8 (temp in d_out)
  char* H8  = X8 + 25165824;               //  8,388,608 int8 (temp in d_out)

  pack_all_kernel<<<dim3(1289), dim3(256), 0, stream>>>(
      W1, E1, Bt1, W2, E2, Bt2, W3, E3, Bt3,
      b1, eb1, bs1, b2, eb2, bs2, b3, eb3, bs3, X, X8, H, H8);

  // Layer 1: i2c + hiddens-add -> A2 (int8)
  gemm_kernel<0><<<dim3(1024), dim3(256), 0, stream>>>(
      X8, Bt1, bs1, H8, A2, nullptr, 3072);

  // Layer 2: h2 -> d_out (int32)
  gemm_kernel<1><<<dim3(1024), dim3(256), 0, stream>>>(
      A2, Bt2, bs2, nullptr, nullptr, out, 1024);

  // Layer 3: reads h2 from d_out (int32), writes out region (int32)
  gemm3_kernel<<<dim3(512), dim3(256), 0, stream>>>(
      out, Bt3, bs3, out + 8388608);
}

// Round 10
// 306.756 us; speedup vs baseline: 1.1437x; 1.0088x over previous
//
#include <hip/hip_runtime.h>

typedef int v4i  __attribute__((ext_vector_type(4)));
typedef int v16i __attribute__((ext_vector_type(16)));

__device__ __forceinline__ int pack4i(int a, int b, int c, int d) {
  return (a & 255) | ((b & 255) << 8) | ((c & 255) << 16) | ((d & 255) << 24);
}
// SWAR per-byte add (mod-256 per lane-byte)
__device__ __forceinline__ int badd4(int a, int b) {
  return ((a & 0x7f7f7f7f) + (b & 0x7f7f7f7f)) ^ ((a ^ b) & 0x80808080);
}

__device__ __forceinline__ void async_ld16(const void* g, void* l) {
  __builtin_amdgcn_global_load_lds(
      (const __attribute__((address_space(1))) void*)g,
      (__attribute__((address_space(3))) void*)l, 16, 0, 0);
}

// ---------------------------------------------------------------------------
// Pack (W + E) -> int8, transposed Bt[n][k] (row stride K bytes).
// Tile: 64 n x 256 k per block, 256 threads. Zero-pads n >= N rows.
// ---------------------------------------------------------------------------
__device__ void pack_tile(const int* __restrict__ W, const int* __restrict__ E,
                          char* __restrict__ Bt, int K, int N,
                          int nx, int ky, char* lin) {
  const int t = threadIdx.x;
  const int n0 = nx * 64, k0 = ky * 256;
  {
    const int kk = t >> 2, c = t & 3;
    for (int p = 0; p < 4; ++p) {
      const int k = kk + (p << 6);
      const long grow = (long)(k0 + k) * N;
      #pragma unroll
      for (int i = 0; i < 4; ++i) {
        const int nl = (c << 4) + (i << 2);
        const int ng = n0 + nl;
        int a0, a1, a2, a3;
        if (ng + 3 < N) {
          int4 wv = *(const int4*)(W + grow + ng);
          int4 ev = *(const int4*)(E + grow + ng);
          a0 = wv.x + ev.x; a1 = wv.y + ev.y; a2 = wv.z + ev.z; a3 = wv.w + ev.w;
        } else {
          a0 = (ng + 0 < N) ? W[grow + ng + 0] + E[grow + ng + 0] : 0;
          a1 = (ng + 1 < N) ? W[grow + ng + 1] + E[grow + ng + 1] : 0;
          a2 = (ng + 2 < N) ? W[grow + ng + 2] + E[grow + ng + 2] : 0;
          a3 = (ng + 3 < N) ? W[grow + ng + 3] + E[grow + ng + 3] : 0;
        }
        *(int*)(lin + k * 68 + nl) = pack4i(a0, a1, a2, a3);
      }
    }
  }
  __syncthreads();
  {
    const int n = t & 63, kq = t >> 6;
    char* dst = Bt + (long)(n0 + n) * K + k0 + (kq << 6);
    int outv[16];
    #pragma unroll
    for (int g = 0; g < 16; ++g) {
      const int k = (kq << 6) + (g << 2);
      outv[g] = pack4i(lin[(k + 0) * 68 + n], lin[(k + 1) * 68 + n],
                       lin[(k + 2) * 68 + n], lin[(k + 3) * 68 + n]);
    }
    #pragma unroll
    for (int g = 0; g < 4; ++g)
      *(int4*)(dst + (g << 4)) =
          make_int4(outv[g * 4], outv[g * 4 + 1], outv[g * 4 + 2], outv[g * 4 + 3]);
  }
}

// ---------------------------------------------------------------------------
// Barrier-free per-wave async narrowing copy (int32 -> int8).
// Each wave owns 3 private 4 KB LDS stages; chunk = 1024 ints (4 KB in, 1 KB
// out). issue(c+2) while consuming c. The DMA->ds_read hazard is fenced by an
// EXPLICIT wave-local s_waitcnt vmcnt(8) (the compiler does NOT fence LDS-DMA
// vs ds_read on its own — R9 failure). Per iter exactly 4 DMAs + 4 stores
// enter vmcnt in order; tail after D(c) at the wait is always >= 8, so
// vmcnt(8) guarantees chunk c's DMAs have landed.
// ---------------------------------------------------------------------------
__device__ void pack_async(const int* __restrict__ src, char* __restrict__ dst,
                           long base, int chunks, char* wbase, int lane) {
  auto issue = [&](int c) {
    char* stg = wbase + (c % 3) * 4096;
    const int* g = src + base + (long)c * 1024 + lane * 4;
    #pragma unroll
    for (int s = 0; s < 4; ++s)
      async_ld16(g + s * 256, stg + s * 1024);   // lands at stg+s*1024+lane*16
  };
  issue(0);
  issue(1);
  for (int c = 0; c < chunks; ++c) {
    if (c + 2 < chunks) issue(c + 2);
    asm volatile("s_waitcnt vmcnt(8)" ::: "memory");   // chunk c's DMAs done
    const char* stg = wbase + (c % 3) * 4096;
    const long ob = base + (long)c * 1024;       // dst byte offset
    #pragma unroll
    for (int s = 0; s < 4; ++s) {
      int4 v = *(const int4*)(stg + s * 1024 + lane * 16);
      *(int*)(dst + ob + s * 256 + lane * 4) = pack4i(v.x, v.y, v.z, v.w);
    }
  }
}

// ---------------------------------------------------------------------------
// pack_all: weight tiles + biases + per-wave async X->X8 / H->H8.
// bid 0..264: weights/bias. 265..776: X (512 blocks, 4 waves x 12 chunks).
// 777..1032: H (256 blocks, 4 waves x 8 chunks).
// ---------------------------------------------------------------------------
__global__ __launch_bounds__(256) void pack_all_kernel(
    const int* W1, const int* E1, char* Bt1,
    const int* W2, const int* E2, char* Bt2,
    const int* W3, const int* E3, char* Bt3,
    const int* b1, const int* eb1, int* bs1,
    const int* b2, const int* eb2, int* bs2,
    const int* b3, const int* eb3, int* bs3,
    const int* X, char* X8, const int* H, char* H8) {
  __shared__ __align__(16) char smem[49152];
  const int bid = blockIdx.x;
  if (bid < 192) {
    pack_tile(W1, E1, Bt1, 3072, 1024, bid % 16, bid / 16, smem);
  } else if (bid < 256) {
    const int l = bid - 192;
    pack_tile(W2, E2, Bt2, 1024, 1024, l % 16, l / 16, smem);
  } else if (bid < 264) {
    const int l = bid - 256;
    pack_tile(W3, E3, Bt3, 1024, 100, l & 1, l >> 1, smem);
  } else if (bid == 264) {
    const int t = threadIdx.x;
    for (int i = t; i < 1024; i += 256) {
      bs1[i] = b1[i] + eb1[i];
      bs2[i] = b2[i] + eb2[i];
    }
    for (int i = t; i < 128; i += 256)
      bs3[i] = (i < 100) ? (b3[i] + eb3[i]) : 0;
  } else if (bid < 777) {
    // X: 25,165,824 ints = 24576 chunks; block = 48 chunks (4 waves x 12)
    const int b = bid - 265;
    const int t = threadIdx.x, w = t >> 6, lane = t & 63;
    pack_async(X, X8, ((long)b * 48 + w * 12) * 1024, 12,
               smem + w * 12288, lane);
  } else {
    // H: 8,388,608 ints = 8192 chunks; block = 32 chunks (4 waves x 8)
    const int b = bid - 777;
    const int t = threadIdx.x, w = t >> 6, lane = t & 63;
    pack_async(H, H8, ((long)b * 32 + w * 8) * 1024, 8,
               smem + w * 12288, lane);
  }
}

// ---------------------------------------------------------------------------
// GEMM: 64x128 tile, BK=64, 256 thr (4 waves, each 64x32), 2-stage LDS dbuf
// (verified R5/R8 shape). Grid 1024; mt = bid&127 so the 8 blocks sharing an
// A-tile are congruent mod 8 -> same XCD L2.
// EPI 0: A8out = trunc8(acc+bs) SWAR+ H8, int8, via LDS transpose  (layer 1)
// EPI 1: Iout  = trunc8(acc+bs) as int32, direct                   (layer 2)
// ---------------------------------------------------------------------------
template<int EPI>
__global__ __launch_bounds__(256, 4) void gemm_kernel(
    const char* __restrict__ A, const char* __restrict__ Btg,
    const int* __restrict__ bsum, const char* __restrict__ H8,
    char* __restrict__ A8out, int* __restrict__ Iout, const int K) {
  // stage: As [64][80] (5120) + Bs [128][80] (10240) = 15360; x2 = 30720
  __shared__ __align__(16) char smem[30720];

  const int t = threadIdx.x;
  const int bid = blockIdx.x;
  const int mt = bid & 127, nt = bid >> 7;
  const long m0 = (long)mt << 6;
  const int n0 = nt << 7;

  const int lane = t & 63, w = t >> 6;
  const int lc = lane & 31, hg = lane >> 5;

  v16i acc[2] = {};

  // A staging: 64 rows x 4 thr x 16B ; B staging: 128 rows x 2 thr x 32B
  const int am = t >> 2, ah = t & 3;
  const char* Arow = A + (m0 + am) * (long)K + ah * 16;
  const int aoff = am * 80 + ah * 16;
  const int bm = t >> 1, bh = t & 1;
  const char* Brow = Btg + (long)(n0 + bm) * K + bh * 32;
  const int boff = bm * 80 + bh * 32;

  const int abo = lc * 80 + hg * 16;
  const int bbo = (w * 32 + lc) * 80 + hg * 16;

  int4 ar, br0, br1;
  auto LOAD = [&](int kb) {
    ar  = *(const int4*)(Arow + kb);
    br0 = *(const int4*)(Brow + kb);
    br1 = *(const int4*)(Brow + kb + 16);
  };
  auto STORE = [&](int stage) {
    char* base = smem + stage * 15360;
    *(int4*)(base + aoff) = ar;
    *(int4*)(base + 5120 + boff)      = br0;
    *(int4*)(base + 5120 + boff + 16) = br1;
  };

  const int kiters = K >> 6;
  LOAD(0);
  STORE(0);
  __syncthreads();

  for (int kt = 0; kt < kiters; ++kt) {
    if (kt + 1 < kiters) LOAD((kt + 1) << 6);   // in flight during MFMA
    const char* base = smem + (kt & 1) * 15360;
    const char* Ab = base + abo;
    const char* Bb = base + 5120 + bbo;
    #pragma unroll
    for (int ks = 0; ks < 2; ++ks) {
      v4i a0 = *(const v4i*)(Ab + ks * 32);
      v4i a1 = *(const v4i*)(Ab + 32 * 80 + ks * 32);
      v4i b  = *(const v4i*)(Bb + ks * 32);
      acc[0] = __builtin_amdgcn_mfma_i32_32x32x32_i8(a0, b, acc[0], 0, 0, 0);
      acc[1] = __builtin_amdgcn_mfma_i32_32x32x32_i8(a1, b, acc[1], 0, 0, 0);
    }
    if (kt + 1 < kiters) {
      STORE((kt + 1) & 1);   // buffer fenced by previous barrier
      __syncthreads();
    }
  }

  // Epilogue. C/D layout: col = lane&31, row = (reg&3) + 8*(reg>>2) + 4*hg.
  const int gcl = w * 32 + lc;
  const int bs = bsum[n0 + gcl];
  if (EPI == 1) {
    #pragma unroll
    for (int tm = 0; tm < 2; ++tm) {
      #pragma unroll
      for (int r = 0; r < 16; ++r) {
        const int row = tm * 32 + (hg << 2) + (r & 3) + ((r >> 2) << 3);
        Iout[(m0 + row) * 1024 + n0 + gcl] = (int)(signed char)(acc[tm][r] + bs);
      }
    }
  } else {
    __syncthreads();   // smem reused as 64x144 transpose buffer
    #pragma unroll
    for (int tm = 0; tm < 2; ++tm) {
      #pragma unroll
      for (int r = 0; r < 16; ++r) {
        const int row = tm * 32 + (hg << 2) + (r & 3) + ((r >> 2) << 3);
        smem[row * 144 + gcl] = (char)(acc[tm][r] + bs);
      }
    }
    __syncthreads();
    // readout: thread -> row t>>2, 32 bytes at (t&3)*32 ; SWAR-add H8
    const char* src = smem + (t >> 2) * 144 + (t & 3) * 32;
    const long gm = m0 + (t >> 2);
    const long gco = gm * 1024 + n0 + (t & 3) * 32;
    int4 s0 = *(const int4*)(src);
    int4 s1 = *(const int4*)(src + 16);
    int4 h0 = *(const int4*)(H8 + gco);
    int4 h1 = *(const int4*)(H8 + gco + 16);
    s0 = make_int4(badd4(s0.x, h0.x), badd4(s0.y, h0.y),
                   badd4(s0.z, h0.z), badd4(s0.w, h0.w));
    s1 = make_int4(badd4(s1.x, h1.x), badd4(s1.y, h1.y),
                   badd4(s1.z, h1.z), badd4(s1.w, h1.w));
    *(int4*)(A8out + gco)      = s0;
    *(int4*)(A8out + gco + 16) = s1;
  }
}

// ---------------------------------------------------------------------------
// Layer 3: 16x128 tile, 512 blocks (2/CU), mfma_i32_16x16x64_i8, 2-stage.
// A = h2 int32 from d_out, packed to int8 in staging. (Verified R7/R8.)
// ---------------------------------------------------------------------------
__global__ __launch_bounds__(256, 2) void gemm3_kernel(
    const int* __restrict__ h2, const char* __restrict__ Btg,
    const int* __restrict__ bsum, int* __restrict__ Iout) {
  // stage: As 16x80 (1280) + Bs 128x80 (10240) = 11520; x2 = 23040
  __shared__ __align__(16) char smem[23040];
  const int t = threadIdx.x;
  const int m0 = blockIdx.x << 4;
  const int lane = t & 63, w = t >> 6;
  const int l16 = lane & 15, q = lane >> 4;
  v4i acc0 = {}, acc1 = {};

  const int am = t >> 4, ah = t & 15;      // 16 rows x 16 thr x 4 ints
  const int* Arow = h2 + (long)(m0 + am) * 1024 + ah * 4;
  const int aoff = am * 80 + ah * 4;
  const int bm = t >> 1, bh = t & 1;       // 128 rows x 2 thr x 32 B
  const char* Brow = Btg + (long)bm * 1024 + bh * 32;
  const int boff = bm * 80 + bh * 32;

  const int abo  = l16 * 80 + q * 16;
  const int bbo0 = (w * 32 + l16) * 80 + q * 16;
  const int bbo1 = (w * 32 + 16 + l16) * 80 + q * 16;

  int4 ar, br0, br1;
  auto LOAD = [&](int kt) {
    const int kb = kt << 6;
    ar  = *(const int4*)(Arow + kb);
    br0 = *(const int4*)(Brow + kb);
    br1 = *(const int4*)(Brow + kb + 16);
  };
  auto STORE = [&](int stage) {
    char* base = smem + stage * 11520;
    *(int*)(base + aoff) = pack4i(ar.x, ar.y, ar.z, ar.w);
    *(int4*)(base + 1280 + boff)      = br0;
    *(int4*)(base + 1280 + boff + 16) = br1;
  };
  auto MFMA = [&](int stage) {
    const char* base = smem + stage * 11520;
    v4i a  = *(const v4i*)(base + abo);
    v4i b0 = *(const v4i*)(base + 1280 + bbo0);
    v4i b1 = *(const v4i*)(base + 1280 + bbo1);
    acc0 = __builtin_amdgcn_mfma_i32_16x16x64_i8(a, b0, acc0, 0, 0, 0);
    acc1 = __builtin_amdgcn_mfma_i32_16x16x64_i8(a, b1, acc1, 0, 0, 0);
  };

  LOAD(0); STORE(0); __syncthreads();
  for (int kt = 0; kt < 16; ++kt) {
    if (kt + 1 < 16) LOAD(kt + 1);
    MFMA(kt & 1);
    if (kt + 1 < 16) { STORE((kt + 1) & 1); __syncthreads(); }
  }

  const int c0 = w * 32 + l16;       // cols {0-15,32-47,64-79,96-111}
  const int c1 = c0 + 16;            // cols {16-31,48-63,80-95,112-127}
  if (c0 < 100) {
    const int b = bsum[c0];
    #pragma unroll
    for (int r = 0; r < 4; ++r)
      Iout[(long)(m0 + q * 4 + r) * 100 + c0] = (int)(signed char)(acc0[r] + b);
  }
  if (c1 < 100) {
    const int b = bsum[c1];
    #pragma unroll
    for (int r = 0; r < 4; ++r)
      Iout[(long)(m0 + q * 4 + r) * 100 + c1] = (int)(signed char)(acc1[r] + b);
  }
}

// ---------------------------------------------------------------------------
// ws (12.7 MB): Bt1 | Bt2 | Bt3 | bs1 | bs2 | bs3 | A2
// d_out scratch: X8 [0,25.2M) + H8 [25.2M,33.6M) — both dead before L2
// overwrites the region with h2 (launch order on one stream guarantees it).
// ---------------------------------------------------------------------------
extern "C" void kernel_launch(void* const* d_in, const int* in_sizes, int n_in,
                              void* d_out, int out_size, void* d_ws, size_t ws_size,
                              hipStream_t stream) {
  (void)in_sizes; (void)n_in; (void)out_size; (void)ws_size;
  const int* W1  = (const int*)d_in[0];
  const int* b1  = (const int*)d_in[1];
  const int* W2  = (const int*)d_in[2];
  const int* b2  = (const int*)d_in[3];
  const int* W3  = (const int*)d_in[4];
  const int* b3  = (const int*)d_in[5];
  const int* E1  = (const int*)d_in[6];
  const int* eb1 = (const int*)d_in[7];
  const int* E2  = (const int*)d_in[8];
  const int* eb2 = (const int*)d_in[9];
  const int* E3  = (const int*)d_in[10];
  const int* eb3 = (const int*)d_in[11];
  const int* X   = (const int*)d_in[12];   // [8192][3072] int32
  const int* H   = (const int*)d_in[13];   // [8192][1024] int32
  int* out = (int*)d_out;                  // h2 [8192*1024] then out [8192*100]

  char* ws  = (char*)d_ws;
  char* Bt1 = ws;                          // 3,145,728
  char* Bt2 = Bt1 + 3145728;               // 1,048,576
  char* Bt3 = Bt2 + 1048576;               //   131,072 (rows 100..127 zeroed)
  int*  bs1 = (int*)(Bt3 + 131072);        // 1024 ints
  int*  bs2 = bs1 + 1024;                  // 1024 ints
  int*  bs3 = bs2 + 1024;                  //  128 ints
  char* A2  = (char*)(bs3 + 128);          // 8,388,608 int8
  char* X8  = (char*)d_out;                // 25,165,824 int8 (temp in d_out)
  char* H8  = X8 + 25165824;               //  8,388,608 int8 (temp in d_out)

  pack_all_kernel<<<dim3(1033), dim3(256), 0, stream>>>(
      W1, E1, Bt1, W2, E2, Bt2, W3, E3, Bt3,
      b1, eb1, bs1, b2, eb2, bs2, b3, eb3, bs3, X, X8, H, H8);

  // Layer 1: i2c + hiddens-add -> A2 (int8)
  gemm_kernel<0><<<dim3(1024), dim3(256), 0, stream>>>(
      X8, Bt1, bs1, H8, A2, nullptr, 3072);

  // Layer 2: h2 -> d_out (int32)
  gemm_kernel<1><<<dim3(1024), dim3(256), 0, stream>>>(
      A2, Bt2, bs2, nullptr, nullptr, out, 1024);

  // Layer 3: reads h2 from d_out (int32), writes out region (int32)
  gemm3_kernel<<<dim3(512), dim3(256), 0, stream>>>(
      out, Bt3, bs3, out + 8388608);
}